// Round 1
// baseline (38.107 us; speedup 1.0000x reference)
//
#include <hip/hip_runtime.h>
#include <math.h>

#define B_TOTAL 16384
#define NQ 512
#define NUM 3

// One wave (64 lanes) per batch element. Each lane holds 8 confidences in
// registers (n = lane*8 + s). Greedy loop: wave argmax (stable tie-break on
// smaller index), consume (-inf), angular accept test vs accepted set.
__global__ __launch_bounds__(256) void greedy_nms_kernel(
    const float* __restrict__ conf,   // [B, NQ]
    const float* __restrict__ pos,    // [B, NQ, 3]
    float* __restrict__ out)          // [B, NUM, 3]
{
    const int wave = threadIdx.x >> 6;
    const int lane = threadIdx.x & 63;
    const int b = blockIdx.x * 4 + wave;
    if (b >= B_TOTAL) return;

    const float* cb = conf + (size_t)b * NQ;
    const float* pb = pos  + (size_t)b * NQ * 3;

    // coalesced vector load: lane l owns conf[l*8 .. l*8+7]
    const float4* cb4 = reinterpret_cast<const float4*>(cb);
    float4 u0 = cb4[lane * 2 + 0];
    float4 u1 = cb4[lane * 2 + 1];
    float v[8] = {u0.x, u0.y, u0.z, u0.w, u1.x, u1.y, u1.z, u1.w};

    const float thresh = 0.78539816339744830961f; // pi/4 (f32 rounding at use)

    // accepted set; zero vectors auto-pass (acos(0)=pi/2 >= pi/4), which
    // exactly mirrors the reference's `where(ar < count, ang, inf)` masking.
    float a0x = 0.f, a0y = 0.f, a0z = 0.f;
    float a1x = 0.f, a1y = 0.f, a1z = 0.f;
    float a2x = 0.f, a2y = 0.f, a2z = 0.f;
    int count = 0;

    for (int it = 0; it < NQ; ++it) {
        if (count >= NUM) break;

        // lane-local argmax over 8 slots; ascending s keeps smallest n on tie
        float bestv = v[0];
        int   bests = 0;
        #pragma unroll
        for (int s = 1; s < 8; ++s) {
            if (v[s] > bestv) { bestv = v[s]; bests = s; }
        }
        int bestn = lane * 8 + bests;

        // wave butterfly argmax; tie -> smaller n (matches stable argsort)
        #pragma unroll
        for (int off = 32; off > 0; off >>= 1) {
            float ov = __shfl_xor(bestv, off);
            int   on = __shfl_xor(bestn, off);
            if (ov > bestv || (ov == bestv && on < bestn)) {
                bestv = ov; bestn = on;
            }
        }

        // consume the winner (static unroll avoids scratch spill)
        if (lane == (bestn >> 3)) {
            int sl = bestn & 7;
            #pragma unroll
            for (int s = 0; s < 8; ++s)
                if (sl == s) v[s] = -INFINITY;
        }

        // wave-uniform accept test
        float px = pb[bestn * 3 + 0];
        float py = pb[bestn * 3 + 1];
        float pz = pb[bestn * 3 + 2];

        float d0 = fminf(fabsf(a0x * px + a0y * py + a0z * pz), 1.0f);
        float d1 = fminf(fabsf(a1x * px + a1y * py + a1z * pz), 1.0f);
        float d2 = fminf(fabsf(a2x * px + a2y * py + a2z * pz), 1.0f);
        bool add = (acosf(d0) >= thresh) &&
                   (acosf(d1) >= thresh) &&
                   (acosf(d2) >= thresh);

        if (add) {
            if (count == 0)      { a0x = px; a0y = py; a0z = pz; }
            else if (count == 1) { a1x = px; a1y = py; a1z = pz; }
            else                 { a2x = px; a2y = py; a2z = pz; }
            ++count;
        }
    }

    // unfilled slots -> pos[0] of this batch (cand stayed index 0)
    if (count < NUM) {
        float p0x = pb[0], p0y = pb[1], p0z = pb[2];
        if (count == 0) { a0x = p0x; a0y = p0y; a0z = p0z; }
        if (count <= 1) { a1x = p0x; a1y = p0y; a1z = p0z; }
        a2x = p0x; a2y = p0y; a2z = p0z;
    }

    if (lane == 0) {
        float* ob = out + (size_t)b * 9;
        ob[0] = a0x; ob[1] = a0y; ob[2] = a0z;
        ob[3] = a1x; ob[4] = a1y; ob[5] = a1z;
        ob[6] = a2x; ob[7] = a2y; ob[8] = a2z;
    }
}

extern "C" void kernel_launch(void* const* d_in, const int* in_sizes, int n_in,
                              void* d_out, int out_size, void* d_ws, size_t ws_size,
                              hipStream_t stream) {
    const float* pred_logits = (const float*)d_in[0]; // [B, NQ, 1]
    const float* pred_pos    = (const float*)d_in[1]; // [B, NQ, 3]
    // d_in[2] (vps_unique) only defines NUM=3, which is static.
    float* out = (float*)d_out;                       // [B, NUM, 3]

    const int waves_per_block = 4;
    const int grid = (B_TOTAL + waves_per_block - 1) / waves_per_block; // 4096
    greedy_nms_kernel<<<grid, 256, 0, stream>>>(pred_logits, pred_pos, out);
}